// Round 1
// 699.649 us; speedup vs baseline: 1.0462x; 1.0462x over previous
//
#include <hip/hip_runtime.h>

// Output layout in d_out (all float32):
//   [0, M)          rows (out_idx[0]),  M = B*n*n
//   [M, 2M)         cols (out_idx[1])
//   [2M, 2M + M*D)  vals (out_val, row-major [M, D])
//
// Strategy (round 5): single-writer fused pass — vals written EXACTLY once.
//   1. build per-slot edge chains (head[M], next[E] in ws): one atomicExch
//      per edge (head is 8.4 MB -> L2/LLC-resident, cheap).
//   2. fused_vals: grid-stride sweep over all M*(D/4) (q,ch) units. Empty
//      slots (79%) nontemporal-store zeros (this IS the fill — no separate
//      512 MiB memset dispatch); occupied slots walk the chain (mean len
//      1.13) and store the sum. Single writer per unit, no atomics, no
//      inter-kernel ordering dependency on a fill.
//   3. closed-form index fill for rows/cols.
// vs round 4: removes the 512 MiB hipMemsetAsync node and the 113 MiB
// double-write of occupied rows; 8192-block grid-stride replaces the
// 131072-WG 1:1 launch.

typedef float vfloat4 __attribute__((ext_vector_type(4)));

__global__ void build_chain_kernel(const int* __restrict__ ei,
                                   const int* __restrict__ batch,
                                   int* __restrict__ head,
                                   int* __restrict__ next,
                                   int E, int n, int n2) {
    int e = blockIdx.x * blockDim.x + threadIdx.x;
    if (e >= E) return;
    int r = ei[e];
    int c = ei[E + e];
    int g = batch[r];
    int pos = g * n2 + (r - g * n) * n + (c - g * n);
    next[e] = atomicExch(&head[pos], e);
}

// One (q,ch) unit = one float4 of the output row. Every unit is stored
// exactly once: zeros (empty slot) or the chain sum (occupied). Wave of 64
// lanes covers 4 consecutive slots -> contiguous 1 KiB nontemporal store.
// Chain walk: ea row load (256 B coalesced across the slot's 16 lanes) and
// next[e] (broadcast 4 B) issue together -> one latency round for the 88%
// of occupied slots with chain length 1.
template <int CHUNKS>
__global__ __launch_bounds__(256) void fused_vals_kernel(
        const float* __restrict__ ea,
        const int* __restrict__ head,
        const int* __restrict__ next,
        float* __restrict__ vals,
        long long total, int D) {
    const long long stride = (long long)gridDim.x * blockDim.x;
    for (long long tid = (long long)blockIdx.x * blockDim.x + threadIdx.x;
         tid < total; tid += stride) {
        unsigned q, ch;
        if (CHUNKS > 0) {
            q  = (unsigned)(tid / CHUNKS);          // constexpr -> shift
            ch = (unsigned)tid & (unsigned)(CHUNKS - 1);
        } else {
            unsigned chunks = (unsigned)(D >> 2);
            q  = (unsigned)(tid / chunks);
            ch = (unsigned)(tid - (long long)q * chunks);
        }
        int e = head[q];
        vfloat4 acc = {0.f, 0.f, 0.f, 0.f};
        while (e >= 0) {
            const vfloat4 v = *(const vfloat4*)(ea + (size_t)e * D + ch * 4);
            int nx = next[e];   // independent of v -> overlapped by scheduler
            acc += v;
            e = nx;
        }
        __builtin_nontemporal_store(acc, (vfloat4*)(vals + (size_t)q * D + ch * 4));
    }
}

__global__ void fill_idx_kernel(float* __restrict__ rows,
                                float* __restrict__ cols,
                                int M, int n, int n2) {
    int q0 = (blockIdx.x * blockDim.x + threadIdx.x) * 4;
    if (q0 >= M) return;
    float4 rv, cv;
    int q = q0;
    rv.x = (float)(q / n); cv.x = (float)((q / n2) * n + (q % n)); q++;
    rv.y = (float)(q / n); cv.y = (float)((q / n2) * n + (q % n)); q++;
    rv.z = (float)(q / n); cv.z = (float)((q / n2) * n + (q % n)); q++;
    rv.w = (float)(q / n); cv.w = (float)((q / n2) * n + (q % n));
    *(float4*)(rows + q0) = rv;
    *(float4*)(cols + q0) = cv;
}

// ---------- fallback (round-1 verified path) if ws is too small ----------
__global__ void scatter_add_kernel(const int* __restrict__ ei,
                                   const float* __restrict__ ea,
                                   const int* __restrict__ batch,
                                   float* __restrict__ vals,
                                   int E, int D, int n, int n2) {
    int chunksPerEdge = D >> 2;
    long long tid = (long long)blockIdx.x * blockDim.x + threadIdx.x;
    int e = (int)(tid / chunksPerEdge);
    int ch = (int)(tid % chunksPerEdge);
    if (e >= E) return;
    int r = ei[e];
    int c = ei[E + e];
    int g = batch[r];
    long long pos = (long long)g * n2 + (long long)(r - g * n) * n + (long long)(c - g * n);
    float4 src = *(const float4*)(ea + (long long)e * D + ch * 4);
    float* dst = vals + pos * D + ch * 4;
    atomicAdd(dst + 0, src.x);
    atomicAdd(dst + 1, src.y);
    atomicAdd(dst + 2, src.z);
    atomicAdd(dst + 3, src.w);
}
// -------------------------------------------------------------------------

extern "C" void kernel_launch(void* const* d_in, const int* in_sizes, int n_in,
                              void* d_out, int out_size, void* d_ws, size_t ws_size,
                              hipStream_t stream) {
    const int* edge_index = (const int*)d_in[0];    // [2, E]
    const float* edge_attr = (const float*)d_in[1]; // [E, D]
    const int* batch = (const int*)d_in[2];         // [B*n]

    const int E  = in_sizes[0] / 2;
    const int D  = in_sizes[1] / E;
    const int M  = out_size / (D + 2);   // B*n*n
    const int BN = in_sizes[2];          // B*n
    const int n  = M / BN;
    const int n2 = n * n;

    float* rows = (float*)d_out;
    float* cols = rows + M;
    float* vals = cols + M;

    const size_t ws_need = ((size_t)M + (size_t)E) * sizeof(int);
    if (ws_size >= ws_need && (D & 3) == 0) {
        int* head = (int*)d_ws;      // [M]
        int* next = head + M;        // [E]

        // head = -1 everywhere (8 MiB, ~1 µs)
        (void)hipMemsetAsync(head, 0xFF, (size_t)M * sizeof(int), stream);

        {
            int block = 256;
            int grid = (E + block - 1) / block;
            build_chain_kernel<<<grid, block, 0, stream>>>(
                edge_index, batch, head, next, E, n, n2);
        }
        {
            long long total = (long long)M * (D / 4);
            int block = 256;
            int grid = 8192;  // grid-stride: full wave-slot occupancy,
                              // contiguous 32 MiB sweep per iteration
            long long blocks_needed = (total + block - 1) / block;
            if (blocks_needed < grid) grid = (int)blocks_needed;
            if (D == 64) {
                fused_vals_kernel<16><<<grid, block, 0, stream>>>(
                    edge_attr, head, next, vals, total, D);
            } else {
                fused_vals_kernel<0><<<grid, block, 0, stream>>>(
                    edge_attr, head, next, vals, total, D);
            }
        }
        {
            int threads = (M + 3) / 4;
            int block = 256;
            int grid = (threads + block - 1) / block;
            fill_idx_kernel<<<grid, block, 0, stream>>>(rows, cols, M, n, n2);
        }
    } else {
        // Fallback: round-1 verified path.
        (void)hipMemsetAsync(vals, 0, (size_t)M * D * sizeof(float), stream);
        {
            int threads = (M + 3) / 4;
            int block = 256;
            int grid = (threads + block - 1) / block;
            fill_idx_kernel<<<grid, block, 0, stream>>>(rows, cols, M, n, n2);
        }
        {
            long long total = (long long)E * (D / 4);
            int block = 256;
            long long grid = (total + block - 1) / block;
            scatter_add_kernel<<<(int)grid, block, 0, stream>>>(
                edge_index, edge_attr, batch, vals, E, D, n, n2);
        }
    }
}